// Round 3
// baseline (528.114 us; speedup 1.0000x reference)
//
#include <hip/hip_runtime.h>
#include <hip/hip_bf16.h>

#define NB 8192
#define ND 128
#define NC 10000
#define NMT 79                 // class tiles (128 wide), ceil(10000/128)
#define NCPAD (NMT * 128)      // 10112
#define NBT 64                 // batch tiles (8192/128)
#define SLICES 8               // class-tile slices per batch-tile
#define GRID (NBT * SLICES)    // 512 blocks = exactly 2/CU on 256 CUs

typedef short bfrag8 __attribute__((ext_vector_type(8)));  // 8 bf16 (4 VGPRs)
typedef float facc4 __attribute__((ext_vector_type(4)));   // MFMA C/D

__device__ __forceinline__ unsigned short f2bf(float f) {
  union { float f; unsigned u; } v; v.f = f;
  unsigned r = v.u + 0x7FFFu + ((v.u >> 16) & 1u);  // RNE
  return (unsigned short)(r >> 16);
}

// ---- prep job ranges (phase 0, grid-strided over 512 blocks) ------------
#define XJOBS 1024             // 262144 float4 / 256 threads
#define SJOBS 32               // 8192 / 256
#define WJOBS (316 * 4)        // (NCPAD/32) x (128/32) 32x32 transpose tiles
#define TOTJOBS (XJOBS + SJOBS + WJOBS)

// ---- hand-rolled grid barrier -------------------------------------------
// 512 blocks x 66KB LDS = exactly 2 blocks/CU on 256 CUs -> all co-resident
// (launch_bounds(256,2) caps VGPR<=256/wave so nothing else limits).
// Release: __syncthreads drains each wave's vmem; thread0 __threadfence
// (agent-scope: L2 writeback on gfx950) then device-scope atomicAdd.
// Acquire: after spin, __syncthreads + per-thread __threadfence (L1/L2
// invalidate) so cross-XCD reads of xb/Wt/S are fresh. Bounded spin: fail
// visibly (wrong results) rather than hang if co-residency ever breaks.
// Cells are zeroed per iteration by an in-graph hipMemsetAsync.
__device__ __forceinline__ void grid_barrier(unsigned* cell) {
  __syncthreads();
  if (threadIdx.x == 0) {
    __threadfence();
    atomicAdd(cell, 1u);
    int tries = 0;
    while (atomicAdd(cell, 0u) < (unsigned)GRID) {
      __builtin_amdgcn_s_sleep(2);
      if (++tries > 20000000) break;   // safety valve (~0.3 s)
    }
  }
  __syncthreads();
  __threadfence();
}

// ---- GEMM phase: block = (batch-tile bt, slice); jobs = class tiles -----
// Verbatim round-1 gemm_pass body (known-good): Xl staged per phase, Wl
// software-pipelined with raw s_barrier + hand-counted vmcnt (steady-state
// vmcnt(16) in the out phase so the previous tile's 16 output stores stay
// in flight across the barrier; only the 8 W-prefetch gl_lds must land).
// Stores plain, tn-outer/tm-inner for full-line write-combining.
template <int STATS>
__device__ __forceinline__ void gemm_phase(
    const unsigned short* __restrict__ xb,   // [NB][128] bf16
    const unsigned short* __restrict__ Wt,   // [NCPAD][128] bf16
    const float* __restrict__ bias,          // [NC]
    float* __restrict__ S,                   // [NB]
    float* __restrict__ out,                 // [NB][NC]
    unsigned short* Xl, unsigned short* Wl, float* sS) {
  const int bid = blockIdx.x;
  const int slice = bid & (SLICES - 1), bt0 = (bid >> 3) * 128;
  const int tid = threadIdx.x;
  const int w = tid >> 6, l = tid & 63;
  const int lane15 = l & 15, quad = l >> 4;
  const int wm = w >> 1, wn = w & 1;         // wm: class half, wn: batch half

  // ---- stage Xl + first W tile; XOR swizzle j ^= (row&15) ----------------
  #pragma unroll
  for (int i = 0; i < 8; ++i) {
    int bbase = i * 256 + w * 64;            // wave-uniform 16B-block base
    int bi = bbase + l;
    int r = bi >> 4, j = bi & 15;
    int jg = j ^ (r & 15);
    __builtin_amdgcn_global_load_lds(
        (const unsigned int*)(xb + (size_t)(bt0 + r) * ND + jg * 8),
        (unsigned int*)(Xl + bbase * 8), 16, 0, 0);
    __builtin_amdgcn_global_load_lds(
        (const unsigned int*)(Wt + (size_t)(slice * 128 + r) * ND + jg * 8),
        (unsigned int*)(Wl + bbase * 8), 16, 0, 0);
  }
  if (!STATS) {
    if (tid < 128) sS[tid] = S[bt0 + tid];
  }

  float psum[4] = {0.f, 0.f, 0.f, 0.f};
  int first = 1;

  for (int ct = slice; ct < NMT; ct += SLICES) {
    const int ct0 = ct * 128;
    // bias for this job's 4 class quads; NC%16==0 so 16-class tiles are
    // entirely valid or entirely invalid. Issued before the barrier.
    facc4 bias4[4]; int cvalid[4];
    #pragma unroll
    for (int tm = 0; tm < 4; ++tm) {
      int cb = ct0 + wm * 64 + tm * 16 + quad * 4;
      cvalid[tm] = (cb < NC);
      bias4[tm] = cvalid[tm] ? *(const facc4*)(bias + cb)
                             : (facc4){0.f, 0.f, 0.f, 0.f};
    }

    if (first) {
      // full drain: initial gl_lds (+ sS publish via lgkm) -> all ready
      __syncthreads();
      first = 0;
    } else {
      // own W-prefetch (8 gl_lds) must have landed; previous tile's stores
      // (<=16, out phase only) may stay in flight. Wait BEFORE the barrier
      // so every wave's prefetch has landed once all waves pass it.
      if (STATS) {
        asm volatile("s_waitcnt vmcnt(0)" ::: "memory");
      } else {
        asm volatile("s_waitcnt vmcnt(16)" ::: "memory");
      }
      __builtin_amdgcn_sched_barrier(0);
      __builtin_amdgcn_s_barrier();
      __builtin_amdgcn_sched_barrier(0);
    }

    // ---- MFMA: 4 K-steps of 32; wave (wm,wn) owns 64x64 = 4x4 tiles ------
    facc4 acc[4][4];
    #pragma unroll
    for (int a = 0; a < 4; ++a)
      #pragma unroll
      for (int b = 0; b < 4; ++b) acc[a][b] = (facc4){0.f, 0.f, 0.f, 0.f};

    #pragma unroll
    for (int kk = 0; kk < 4; ++kk) {
      bfrag8 af[4], bf[4];
      const int jj = (kk * 4 + quad) ^ lane15;  // swizzled 16B-block in row
      #pragma unroll
      for (int tm = 0; tm < 4; ++tm)
        af[tm] = *(const bfrag8*)(Wl + (wm * 64 + tm * 16 + lane15) * 128 + jj * 8);
      #pragma unroll
      for (int tn = 0; tn < 4; ++tn)
        bf[tn] = *(const bfrag8*)(Xl + (wn * 64 + tn * 16 + lane15) * 128 + jj * 8);
      #pragma unroll
      for (int tm = 0; tm < 4; ++tm)
        #pragma unroll
        for (int tn = 0; tn < 4; ++tn)
          acc[tm][tn] = __builtin_amdgcn_mfma_f32_16x16x32_bf16(
              af[tm], bf[tn], acc[tm][tn], 0, 0, 0);
    }

    // all waves done reading Wl -> safe to restage after this barrier
    __builtin_amdgcn_sched_barrier(0);
    __builtin_amdgcn_s_barrier();
    __builtin_amdgcn_sched_barrier(0);

    // ---- issue next W tile; flies under the epilogue ---------------------
    if (ct + SLICES < NMT) {
      const int nct0 = (ct + SLICES) * 128;
      #pragma unroll
      for (int i = 0; i < 8; ++i) {
        int bbase = i * 256 + w * 64;
        int bi = bbase + l;
        int r = bi >> 4, j = bi & 15;
        int jg = j ^ (r & 15);
        __builtin_amdgcn_global_load_lds(
            (const unsigned int*)(Wt + (size_t)(nct0 + r) * ND + jg * 8),
            (unsigned int*)(Wl + bbase * 8), 16, 0, 0);
      }
    }

    // ---- epilogue --------------------------------------------------------
    if (STATS) {
      #pragma unroll
      for (int tn = 0; tn < 4; ++tn) {
        float p = 0.f;
        #pragma unroll
        for (int tm = 0; tm < 4; ++tm) {
          if (cvalid[tm]) {
            #pragma unroll
            for (int rg = 0; rg < 4; ++rg)
              p += __expf(acc[tm][tn][rg] + bias4[tm][rg]);
          }
        }
        psum[tn] += p;
      }
    } else {
      // tn outer / tm inner: the 4 stores per tn hit bytes [0,64),[64,128),
      // [128,192),[192,256) of the same 16 rows back-to-back -> full-line
      // write-combining in L2. Plain stores (no nt streaming hint).
      #pragma unroll
      for (int tn = 0; tn < 4; ++tn) {
        int b = wn * 64 + tn * 16 + lane15;
        float Sv = sS[b];
        float* orow = out + (size_t)(bt0 + b) * NC;
        #pragma unroll
        for (int tm = 0; tm < 4; ++tm) {
          if (cvalid[tm]) {
            int cb = ct0 + wm * 64 + tm * 16 + quad * 4;
            facc4 o;
            #pragma unroll
            for (int rg = 0; rg < 4; ++rg) {
              float e = __expf(acc[tm][tn][rg] + bias4[tm][rg]);
              o[rg] = -__logf(Sv - e);
            }
            *(facc4*)(orow + cb) = o;
          }
        }
      }
    }
  }

  if (STATS) {
    #pragma unroll
    for (int tn = 0; tn < 4; ++tn) {
      float p = psum[tn];
      p += __shfl_xor(p, 16, 64);
      p += __shfl_xor(p, 32, 64);
      if (quad == 0)
        atomicAdd(&S[bt0 + wn * 64 + tn * 16 + lane15], p);
    }
  }
}

// ---- fused kernel: prep | grid-bar | stats | grid-bar | out -------------
__global__ __launch_bounds__(256, 2) void fused(
    const float* __restrict__ x,             // [8192][128]
    const float* __restrict__ W,             // [128][10000]
    const float* __restrict__ bias,          // [10000]
    unsigned short* __restrict__ xb,         // [NB][128] bf16 (ws)
    unsigned short* __restrict__ Wt,         // [NCPAD][128] bf16 (ws)
    float* __restrict__ S,                   // [NB] (ws)
    unsigned* __restrict__ bar,              // [2] (ws, memset 0 in-graph)
    float* __restrict__ out) {               // [NB][NC]
  __shared__ __align__(16) unsigned short Xl[128 * 128];  // 32 KB
  __shared__ __align__(16) unsigned short Wl[128 * 128];  // 32 KB
  __shared__ float sS[128];

  const int bid = blockIdx.x, tid = threadIdx.x;

  // ---- phase 0: prep (x->bf16 | S=0 | W transpose+convert) ---------------
  {
    float (*t)[33] = (float (*)[33])Xl;      // alias transpose tile into Xl
    for (int job = bid; job < TOTJOBS; job += GRID) {
      if (job < XJOBS) {
        int i = job * 256 + tid;             // 4 floats / thread
        float4 v = ((const float4*)x)[i];
        ushort4 o;
        o.x = f2bf(v.x); o.y = f2bf(v.y); o.z = f2bf(v.z); o.w = f2bf(v.w);
        ((ushort4*)xb)[i] = o;
      } else if (job < XJOBS + SJOBS) {
        S[(job - XJOBS) * 256 + tid] = 0.f;  // ws is re-poisoned 0xAA
      } else {
        int j = job - XJOBS - SJOBS;
        int c0 = (j >> 2) * 32, r0 = (j & 3) * 32;
        int tx = tid & 31, ty = tid >> 5;    // (32, 8)
        #pragma unroll
        for (int i = 0; i < 4; ++i) {
          int r = r0 + ty + i * 8, c = c0 + tx;  // r < 128 always
          t[ty + i * 8][tx] = (c < NC) ? W[(size_t)r * NC + c] : 0.f;
        }
        __syncthreads();
        #pragma unroll
        for (int i = 0; i < 4; ++i) {
          int c = c0 + ty + i * 8, r = r0 + tx;  // c < NCPAD
          Wt[(size_t)c * ND + r] = f2bf(t[tx][ty + i * 8]);
        }
        __syncthreads();                     // t reused by next job
      }
    }
  }

  grid_barrier(&bar[0]);                     // xb/Wt/S=0 globally visible

  // ---- phase 1: stats (S[b] = sum_c exp(logit)) --------------------------
  gemm_phase<1>(xb, Wt, bias, S, out, Xl, Wl, sS);

  grid_barrier(&bar[1]);                     // S finalized

  // ---- phase 2: out = -log(S - exp(logit)) -------------------------------
  gemm_phase<0>(xb, Wt, bias, S, out, Xl, Wl, sS);
}

extern "C" void kernel_launch(void* const* d_in, const int* in_sizes, int n_in,
                              void* d_out, int out_size, void* d_ws, size_t ws_size,
                              hipStream_t stream) {
  const float* x    = (const float*)d_in[0];   // [8192][128]
  const float* W    = (const float*)d_in[1];   // [128][10000]
  const float* bias = (const float*)d_in[2];   // [10000]
  float* out = (float*)d_out;

  char* ws = (char*)d_ws;
  unsigned short* xb = (unsigned short*)ws;                          // 2 MB
  unsigned short* Wt = (unsigned short*)(ws + (size_t)NB * ND * 2);  // 2.53 MB
  float* S = (float*)(ws + (size_t)NB * ND * 2 + (size_t)NCPAD * ND * 2);
  unsigned* bar = (unsigned*)((char*)(S + NB));  // 2 cells, 256B-aligned

  hipMemsetAsync(bar, 0, 64, stream);        // in-graph: reset per replay
  fused<<<GRID, 256, 0, stream>>>(x, W, bias, xb, Wt, S, bar, out);
}

// Round 4
// 402.323 us; speedup vs baseline: 1.3127x; 1.3127x over previous
//
#include <hip/hip_runtime.h>
#include <hip/hip_bf16.h>

#define NB 8192
#define ND 128
#define NC 10000
#define NMT 79                 // class tiles (128 wide), ceil(10000/128)
#define NCPAD (NMT * 128)      // 10112
#define BT 64                  // batch rows per GEMM block (was 128)
#define NBT (NB / BT)          // 128 batch tiles
#define SLICES 6               // class-tile slices per batch-tile
#define GRID (NBT * SLICES)    // 768 blocks = exactly 3/CU on 256 CUs

#define LOG2E 1.4426950408889634f
#define NLN2  (-0.6931471805599453f)

typedef short bfrag8 __attribute__((ext_vector_type(8)));  // 8 bf16 (4 VGPRs)
typedef float facc4 __attribute__((ext_vector_type(4)));   // MFMA C/D

__device__ __forceinline__ unsigned short f2bf(float f) {
  union { float f; unsigned u; } v; v.f = f;
  unsigned r = v.u + 0x7FFFu + ((v.u >> 16) & 1u);  // RNE
  return (unsigned short)(r >> 16);
}

// ---- fused prep: x->bf16 | S=0 | W transpose+convert, by block range ----
// W is pre-scaled by log2e so the GEMM epilogues use native v_exp_f32 /
// v_log_f32 (exp2/log2) with no per-value range-conversion mul. Both GEMM
// passes see the same scaled Wt -> logits bitwise identical -> the exp
// cancellation in -log(S - e) stays exact.
#define XJOBS 1024             // 262144 float4 / 256 threads
#define SJOBS 32               // 8192 / 256
#define WJOBS (316 * 4)        // (NCPAD/32) x (128/32) 32x32 transpose tiles

__global__ void prep_kernel(const float* __restrict__ x,
                            const float* __restrict__ W,
                            unsigned short* __restrict__ xb,
                            unsigned short* __restrict__ Wt,
                            float* __restrict__ S) {
  int job = blockIdx.x, tid = threadIdx.x;
  if (job < XJOBS) {
    int i = job * 256 + tid;                 // 4 floats / thread
    float4 v = ((const float4*)x)[i];
    ushort4 o;
    o.x = f2bf(v.x); o.y = f2bf(v.y); o.z = f2bf(v.z); o.w = f2bf(v.w);
    ((ushort4*)xb)[i] = o;
  } else if (job < XJOBS + SJOBS) {
    S[(job - XJOBS) * 256 + tid] = 0.f;      // ws is re-poisoned 0xAA
  } else {
    __shared__ float t[32][33];
    int j = job - XJOBS - SJOBS;
    int c0 = (j >> 2) * 32, r0 = (j & 3) * 32;
    int tx = tid & 31, ty = tid >> 5;        // (32, 8)
    #pragma unroll
    for (int i = 0; i < 4; ++i) {
      int r = r0 + ty + i * 8, c = c0 + tx;  // r < 128 always
      t[ty + i * 8][tx] = (c < NC) ? W[(size_t)r * NC + c] : 0.f;
    }
    __syncthreads();
    #pragma unroll
    for (int i = 0; i < 4; ++i) {
      int c = c0 + ty + i * 8, r = r0 + tx;  // c < NCPAD
      Wt[(size_t)c * ND + r] = f2bf(t[tx][ty + i * 8] * LOG2E);
    }
  }
}

// ---- GEMM pass: block = (batch-tile 64, slice); jobs = class tiles ------
// 48KB LDS (Xl 16K + Wl 32K) -> 3 blocks/CU (was 2 at 64KB): round-3 fused
// counters showed latency-bound (MfmaUtil 6.7%, VALU 23%, HBM 17%, occ 22%)
// so the lever is resident waves. Wave (wm,wn) owns 64 classes x 32 batch
// (acc[4][2]). Wl software-pipelined with raw s_barrier + counted vmcnt:
// steady-state vmcnt(8) in the out pass keeps the previous tile's 8 output
// stores in flight across the barrier (only the 8 W-prefetch gl_lds must
// land; vmcnt is in-order so >=8 younger ops guarantee the oldest 8 gl_lds
// are drained). Stores plain, tn-outer/tm-inner: per row each wave writes
// 256B contiguous -> two full 128B lines -> L2 write-combines (round-3
// WRITE_SIZE == ideal confirmed).
template <int STATS>
__global__ __launch_bounds__(256, 3) void gemm_pass(
    const unsigned short* __restrict__ xb,   // [NB][128] bf16
    const unsigned short* __restrict__ Wt,   // [NCPAD][128] bf16 (x log2e)
    const float* __restrict__ bias,          // [NC]
    float* __restrict__ S,                   // [NB]
    float* __restrict__ out) {               // [NB][NC]
  __shared__ __align__(16) unsigned short Xl[BT * 128];   // 16 KB
  __shared__ __align__(16) unsigned short Wl[128 * 128];  // 32 KB
  __shared__ float sS[BT];

  const int bid = blockIdx.x;
  const int slice = bid % SLICES, bt0 = (bid / SLICES) * BT;
  const int tid = threadIdx.x;
  const int w = tid >> 6, l = tid & 63;
  const int lane15 = l & 15, quad = l >> 4;
  const int wm = w >> 1, wn = w & 1;         // wm: class half, wn: batch half

  // ---- stage Xl (4 iters) + first W tile (8 iters); XOR swizzle ---------
  #pragma unroll
  for (int i = 0; i < 4; ++i) {
    int bbase = i * 256 + w * 64;            // wave-uniform 16B-block base
    int bi = bbase + l;
    int r = bi >> 4, j = bi & 15;
    int jg = j ^ (r & 15);
    __builtin_amdgcn_global_load_lds(
        (const unsigned int*)(xb + (size_t)(bt0 + r) * ND + jg * 8),
        (unsigned int*)(Xl + bbase * 8), 16, 0, 0);
  }
  #pragma unroll
  for (int i = 0; i < 8; ++i) {
    int bbase = i * 256 + w * 64;
    int bi = bbase + l;
    int r = bi >> 4, j = bi & 15;
    int jg = j ^ (r & 15);
    __builtin_amdgcn_global_load_lds(
        (const unsigned int*)(Wt + (size_t)(slice * 128 + r) * ND + jg * 8),
        (unsigned int*)(Wl + bbase * 8), 16, 0, 0);
  }
  if (!STATS) {
    if (tid < BT) sS[tid] = S[bt0 + tid];
  }

  float psum[2] = {0.f, 0.f};
  int first = 1;

  for (int ct = slice; ct < NMT; ct += SLICES) {
    const int ct0 = ct * 128;
    // bias (x log2e) for this job's 4 class quads; NC%16==0 so 16-class
    // tiles are entirely valid or entirely invalid. Issued pre-barrier.
    facc4 bias4[4]; int cvalid[4];
    #pragma unroll
    for (int tm = 0; tm < 4; ++tm) {
      int cb = ct0 + wm * 64 + tm * 16 + quad * 4;
      cvalid[tm] = (cb < NC);
      facc4 bv = cvalid[tm] ? *(const facc4*)(bias + cb)
                            : (facc4){0.f, 0.f, 0.f, 0.f};
      bias4[tm] = bv * LOG2E;
    }

    if (first) {
      // full drain: initial 12 gl_lds (+ sS publish via lgkm) -> all ready
      __syncthreads();
      first = 0;
    } else {
      // own W-prefetch (8 gl_lds) must have landed; previous tile's stores
      // (<=8, out pass only) may stay in flight. Wait BEFORE the barrier
      // so every wave's prefetch has landed once all waves pass it.
      if (STATS) {
        asm volatile("s_waitcnt vmcnt(0)" ::: "memory");
      } else {
        asm volatile("s_waitcnt vmcnt(8)" ::: "memory");
      }
      __builtin_amdgcn_sched_barrier(0);
      __builtin_amdgcn_s_barrier();
      __builtin_amdgcn_sched_barrier(0);
    }

    // ---- MFMA: 4 K-steps of 32; wave (wm,wn) owns 64x32 = 4x2 tiles ------
    facc4 acc[4][2];
    #pragma unroll
    for (int a = 0; a < 4; ++a)
      #pragma unroll
      for (int b = 0; b < 2; ++b) acc[a][b] = (facc4){0.f, 0.f, 0.f, 0.f};

    #pragma unroll
    for (int kk = 0; kk < 4; ++kk) {
      bfrag8 af[4], bf[2];
      const int jj = (kk * 4 + quad) ^ lane15;  // swizzled 16B-block in row
      #pragma unroll
      for (int tm = 0; tm < 4; ++tm)
        af[tm] = *(const bfrag8*)(Wl + (wm * 64 + tm * 16 + lane15) * 128 + jj * 8);
      #pragma unroll
      for (int tn = 0; tn < 2; ++tn)
        bf[tn] = *(const bfrag8*)(Xl + (wn * 32 + tn * 16 + lane15) * 128 + jj * 8);
      #pragma unroll
      for (int tm = 0; tm < 4; ++tm)
        #pragma unroll
        for (int tn = 0; tn < 2; ++tn)
          acc[tm][tn] = __builtin_amdgcn_mfma_f32_16x16x32_bf16(
              af[tm], bf[tn], acc[tm][tn], 0, 0, 0);
    }

    // all waves done reading Wl -> safe to restage after this barrier
    __builtin_amdgcn_sched_barrier(0);
    __builtin_amdgcn_s_barrier();
    __builtin_amdgcn_sched_barrier(0);

    // ---- issue next W tile; flies under the epilogue ---------------------
    if (ct + SLICES < NMT) {
      const int nct0 = (ct + SLICES) * 128;
      #pragma unroll
      for (int i = 0; i < 8; ++i) {
        int bbase = i * 256 + w * 64;
        int bi = bbase + l;
        int r = bi >> 4, j = bi & 15;
        int jg = j ^ (r & 15);
        __builtin_amdgcn_global_load_lds(
            (const unsigned int*)(Wt + (size_t)(nct0 + r) * ND + jg * 8),
            (unsigned int*)(Wl + bbase * 8), 16, 0, 0);
      }
    }

    // ---- epilogue: native exp2/log2 (log2e folded into Wt/bias) ----------
    if (STATS) {
      #pragma unroll
      for (int tn = 0; tn < 2; ++tn) {
        float p = 0.f;
        #pragma unroll
        for (int tm = 0; tm < 4; ++tm) {
          if (cvalid[tm]) {
            #pragma unroll
            for (int rg = 0; rg < 4; ++rg)
              p += exp2f(acc[tm][tn][rg] + bias4[tm][rg]);
          }
        }
        psum[tn] += p;
      }
    } else {
      #pragma unroll
      for (int tn = 0; tn < 2; ++tn) {
        int b = wn * 32 + tn * 16 + lane15;
        float Sv = sS[b];
        float* orow = out + (size_t)(bt0 + b) * NC;
        #pragma unroll
        for (int tm = 0; tm < 4; ++tm) {
          if (cvalid[tm]) {
            int cb = ct0 + wm * 64 + tm * 16 + quad * 4;
            facc4 o;
            #pragma unroll
            for (int rg = 0; rg < 4; ++rg) {
              float e = exp2f(acc[tm][tn][rg] + bias4[tm][rg]);
              o[rg] = NLN2 * log2f(Sv - e);
            }
            *(facc4*)(orow + cb) = o;
          }
        }
      }
    }
  }

  if (STATS) {
    #pragma unroll
    for (int tn = 0; tn < 2; ++tn) {
      float p = psum[tn];
      p += __shfl_xor(p, 16, 64);
      p += __shfl_xor(p, 32, 64);
      if (quad == 0)
        atomicAdd(&S[bt0 + wn * 32 + tn * 16 + lane15], p);
    }
  }
}

extern "C" void kernel_launch(void* const* d_in, const int* in_sizes, int n_in,
                              void* d_out, int out_size, void* d_ws, size_t ws_size,
                              hipStream_t stream) {
  const float* x    = (const float*)d_in[0];   // [8192][128]
  const float* W    = (const float*)d_in[1];   // [128][10000]
  const float* bias = (const float*)d_in[2];   // [10000]
  float* out = (float*)d_out;

  char* ws = (char*)d_ws;
  unsigned short* xb = (unsigned short*)ws;                          // 2 MB
  unsigned short* Wt = (unsigned short*)(ws + (size_t)NB * ND * 2);  // 2.53 MB
  float* S = (float*)(ws + (size_t)NB * ND * 2 + (size_t)NCPAD * ND * 2);

  prep_kernel<<<XJOBS + SJOBS + WJOBS, 256, 0, stream>>>(x, W, xb, Wt, S);
  gemm_pass<1><<<GRID, 256, 0, stream>>>(xb, Wt, bias, S, nullptr);
  gemm_pass<0><<<GRID, 256, 0, stream>>>(xb, Wt, bias, S, out);
}